// Round 17
// baseline (1250.076 us; speedup 1.0000x reference)
//
#include <hip/hip_runtime.h>
#include <hip/hip_cooperative_groups.h>

namespace cg = cooperative_groups;

#define T_STEPS 8192
#define SIT     64
#define SS      256
#define S2      512
#define NPL     32000
#define NEV     (2*T_STEPS)
#define MAXLEV  255
#define RELAX   48
#define NKB     (S2/4)
#define WKB     (SIT/4)
#define BQMAX   16
#define CUTN    300
#define NSLICE  4
#define MAXB    4096
#define DIAG    0.8f

typedef __attribute__((ext_vector_type(8))) short short8;
typedef __attribute__((ext_vector_type(4))) float f32x4;

__device__ __forceinline__ float sigmoidf_(float x) {
    return 1.0f / (1.0f + expf(-x));
}
__device__ __forceinline__ float bflo_(unsigned u) { return __uint_as_float(u << 16); }
__device__ __forceinline__ float bfhi_(unsigned u) { return __uint_as_float(u & 0xFFFF0000u); }
__device__ __forceinline__ unsigned short f2bf_(float f) {
    unsigned u = __float_as_uint(f);
    u = u + 0x7FFFu + ((u >> 16) & 1u);
    return (unsigned short)(u >> 16);
}
__device__ __forceinline__ unsigned pk2_(float a, float b) {
    return (unsigned)f2bf_(a) | ((unsigned)f2bf_(b) << 16);
}
__device__ __forceinline__ float dot4_(float4 a, float4 b) {
    return a.x*b.x + a.y*b.y + a.z*b.z + a.w*b.w;
}
__device__ __forceinline__ float loadLLC_(const float* p) {
    return __hip_atomic_load(p, __ATOMIC_RELAXED, __HIP_MEMORY_SCOPE_AGENT);
}
__device__ __forceinline__ void storeLLC_(float* p, float v) {
    __hip_atomic_store(p, v, __ATOMIC_RELAXED, __HIP_MEMORY_SCOPE_AGENT);
}

// ---------------- preprocessing kernels ----------------

__global__ void k_count(const int* __restrict__ b, const int* __restrict__ p, int* cnt) {
    int e = blockIdx.x * blockDim.x + threadIdx.x;
    if (e < NEV) {
        int v = (e & 1) ? p[e >> 1] : b[e >> 1];
        atomicAdd(&cnt[v], 1);
    }
}

__global__ __launch_bounds__(1024) void k_scan(const int* __restrict__ cnt, int* bas, int* cur) {
    __shared__ int partial[1024];
    int tid = threadIdx.x;
    int start = tid * 32;
    int end = start + 32; if (end > NPL) end = NPL;
    int s = 0;
    for (int i = start; i < end; ++i) s += cnt[i];
    partial[tid] = s;
    __syncthreads();
    for (int off = 1; off < 1024; off <<= 1) {
        int v = partial[tid];
        int add = (tid >= off) ? partial[tid - off] : 0;
        __syncthreads();
        partial[tid] = v + add;
        __syncthreads();
    }
    int acc = (tid == 0) ? 0 : partial[tid - 1];
    for (int i = start; i < end; ++i) {
        bas[i] = acc; cur[i] = acc; acc += cnt[i];
    }
}

__global__ void k_place(const int* __restrict__ b, const int* __restrict__ p, int* cur, int* list) {
    int e = blockIdx.x * blockDim.x + threadIdx.x;
    if (e < NEV) {
        int v = (e & 1) ? p[e >> 1] : b[e >> 1];
        int pos = atomicAdd(&cur[v], 1);
        list[pos] = e;
    }
}

__global__ void k_pred(const int* __restrict__ bas, const int* __restrict__ cnt, int* list, int* pred) {
    int v = blockIdx.x * blockDim.x + threadIdx.x;
    if (v >= NPL) return;
    int s0 = bas[v], c = cnt[v];
    for (int i2 = 1; i2 < c; ++i2) {
        int key = list[s0 + i2];
        int j = i2 - 1;
        while (j >= 0 && list[s0 + j] > key) { list[s0 + j + 1] = list[s0 + j]; --j; }
        list[s0 + j + 1] = key;
    }
    int prevS = -1, curS = -1;
    for (int i2 = 0; i2 < c; ++i2) {
        int e = list[s0 + i2];
        int s = e >> 1;
        if (s != curS) { prevS = curS; curS = s; }
        pred[e] = prevS;
    }
}

__global__ __launch_bounds__(1024) void k_levels(const int* __restrict__ pred,
                                                 int* order, int* levelStart, int* numLevels) {
    __shared__ short p0[T_STEPS], p1[T_STEPS];
    __shared__ unsigned char lev[T_STEPS];
    __shared__ int cnts[MAXLEV + 2];
    __shared__ int maxLev;
    __shared__ int changed;
    int tid = threadIdx.x;
    for (int t = tid; t < T_STEPS; t += 1024) {
        p0[t] = (short)pred[2 * t];
        p1[t] = (short)pred[2 * t + 1];
        lev[t] = 1;
    }
    for (int l = tid; l < MAXLEV + 2; l += 1024) cnts[l] = 0;
    if (tid == 0) maxLev = 0;
    __syncthreads();
    for (int r = 0; r < RELAX; ++r) {
        if (tid == 0) changed = 0;
        __syncthreads();
        for (int t = tid; t < T_STEPS; t += 1024) {
            int a = p0[t], b2 = p1[t];
            int la = (a >= 0) ? (int)lev[a] : 0;
            int lb = (b2 >= 0) ? (int)lev[b2] : 0;
            int nl = 1 + (la > lb ? la : lb);
            if (nl > MAXLEV) nl = MAXLEV;
            if (nl > (int)lev[t]) { lev[t] = (unsigned char)nl; changed = 1; }
        }
        __syncthreads();
        int ch = changed;
        __syncthreads();
        if (!ch) break;
    }
    for (int t = tid; t < T_STEPS; t += 1024) {
        atomicAdd(&cnts[lev[t]], 1);
        atomicMax(&maxLev, (int)lev[t]);
    }
    __syncthreads();
    if (tid == 0) {
        int acc = 0;
        levelStart[0] = 0;
        int cut = 0, stopped = 0;
        for (int l = 1; l <= maxLev; ++l) {
            int c = cnts[l];
            if (!stopped) { if (c > CUTN) cut = l; else stopped = 1; }
            cnts[l] = acc;
            acc += c;
            levelStart[l] = acc;
        }
        numLevels[0] = maxLev;
        numLevels[1] = cut;
    }
    __syncthreads();
    for (int t = tid; t < T_STEPS; t += 1024) {
        int pos = atomicAdd(&cnts[lev[t]], 1);
        order[pos] = t;
    }
}

// transpose/compress: Uzr/Uhp row-packed bf16 (phase B), UB* MFMA B-fragment
// order (phase A), W transposed f32. V = U - DIAG*I everywhere.
__global__ void k_trans(const float* __restrict__ Uz, const float* __restrict__ Ur,
                        const float* __restrict__ Uh, const float* __restrict__ Wz,
                        const float* __restrict__ Wr, const float* __restrict__ Wh,
                        uint4* __restrict__ UzrP, uint2* __restrict__ UhP,
                        unsigned short* __restrict__ UBz, unsigned short* __restrict__ UBr,
                        unsigned short* __restrict__ UBh,
                        float* WzT, float* WrT, float* WhT) {
    int y = blockIdx.y;
    int idx = blockIdx.x * blockDim.x + threadIdx.x;
    if (y == 0) {
        if (idx < S2 * NKB) {
            int kb = idx >> 9, i2 = idx & (S2 - 1);
            int k = kb * 4;
            float z0 = Uz[i2 * S2 + k + 0] - ((i2 == k + 0) ? DIAG : 0.f);
            float z1 = Uz[i2 * S2 + k + 1] - ((i2 == k + 1) ? DIAG : 0.f);
            float z2 = Uz[i2 * S2 + k + 2] - ((i2 == k + 2) ? DIAG : 0.f);
            float z3 = Uz[i2 * S2 + k + 3] - ((i2 == k + 3) ? DIAG : 0.f);
            float r0 = Ur[i2 * S2 + k + 0] - ((i2 == k + 0) ? DIAG : 0.f);
            float r1 = Ur[i2 * S2 + k + 1] - ((i2 == k + 1) ? DIAG : 0.f);
            float r2 = Ur[i2 * S2 + k + 2] - ((i2 == k + 2) ? DIAG : 0.f);
            float r3 = Ur[i2 * S2 + k + 3] - ((i2 == k + 3) ? DIAG : 0.f);
            uint4 o;
            o.x = pk2_(z0, z1); o.y = pk2_(z2, z3);
            o.z = pk2_(r0, r1); o.w = pk2_(r2, r3);
            UzrP[idx] = o;
        }
    } else if (y == 1) {
        if (idx < S2 * NKB) {
            int kb = idx >> 9, i2 = idx & (S2 - 1);
            int k = kb * 4;
            float h0 = Uh[i2 * S2 + k + 0] - ((i2 == k + 0) ? DIAG : 0.f);
            float h1 = Uh[i2 * S2 + k + 1] - ((i2 == k + 1) ? DIAG : 0.f);
            float h2 = Uh[i2 * S2 + k + 2] - ((i2 == k + 2) ? DIAG : 0.f);
            float h3 = Uh[i2 * S2 + k + 3] - ((i2 == k + 3) ? DIAG : 0.f);
            uint2 o;
            o.x = pk2_(h0, h1); o.y = pk2_(h2, h3);
            UhP[idx] = o;
        }
    } else if (y <= 4) {
        const float* S = (y == 2) ? Wz : (y == 3) ? Wr : Wh;
        float*       D = (y == 2) ? WzT : (y == 3) ? WrT : WhT;
        if (idx < S2 * SIT) {
            int i2 = idx / SIT, k = idx % SIT;
            D[((k >> 2) * S2 + i2) * 4 + (k & 3)] = S[idx];
        }
    } else {
        const float* S = (y == 5) ? Uz : (y == 6) ? Ur : Uh;
        unsigned short* D = (y == 5) ? UBz : (y == 6) ? UBr : UBh;
        if (idx < S2 * S2) {
            int j = idx & 7;
            int lane = (idx >> 3) & 63;
            int ks = (idx >> 9) & 15;
            int nb = idx >> 13;
            int row = nb * 16 + (lane & 15);
            int col = ks * 32 + (lane >> 4) * 8 + j;
            float v = S[row * S2 + col] - ((row == col) ? DIAG : 0.f);
            D[idx] = f2bf_(v);
        }
    }
}

__global__ void k_copy(const float4* __restrict__ src, float4* dst, int n4) {
    int i = blockIdx.x * blockDim.x + threadIdx.x;
    if (i < n4) dst[i] = src[i];
}

// XP = W@x + bias for all steps
__global__ __launch_bounds__(512) void k_xp(
    const float* __restrict__ x,
    const float* __restrict__ WzT, const float* __restrict__ WrT, const float* __restrict__ WhT,
    const float* __restrict__ bz, const float* __restrict__ br, const float* __restrict__ bh,
    float* __restrict__ XPz, float* __restrict__ XPr, float* __restrict__ XPh)
{
    __shared__ float xs[16][SIT];
    const int i = threadIdx.x;
    const int tile = blockIdx.x;
    const float4* Wz4 = (const float4*)WzT;
    const float4* Wr4 = (const float4*)WrT;
    const float4* Wh4 = (const float4*)WhT;
    const float bzi = bz[i], bri = br[i], bhi = bh[i];

    for (int idx = i; idx < 16 * SIT; idx += 512) {
        int j = idx >> 6, k = idx & (SIT - 1);
        xs[j][k] = x[(tile * 16 + j) * SIT + k];
    }
    __syncthreads();
    float za[16], ra[16], ha[16];
#pragma unroll
    for (int j = 0; j < 16; ++j) { za[j] = 0.f; ra[j] = 0.f; ha[j] = 0.f; }
    for (int kb = 0; kb < WKB; ++kb) {
        float4 wz = Wz4[kb * S2 + i];
        float4 wr = Wr4[kb * S2 + i];
        float4 wh = Wh4[kb * S2 + i];
#pragma unroll
        for (int j = 0; j < 16; ++j) {
            float4 x4 = *(const float4*)(&xs[j][kb * 4]);
            za[j] += dot4_(wz, x4);
            ra[j] += dot4_(wr, x4);
            ha[j] += dot4_(wh, x4);
        }
    }
#pragma unroll
    for (int j = 0; j < 16; ++j) {
        int t = tile * 16 + j;
        XPz[t * S2 + i] = za[j] + bzi;
        XPr[t * S2 + i] = ra[j] - bri;
        XPh[t * S2 + i] = ha[j] + bhi;
    }
}

// ---------------- main cooperative kernel ----------------

// Flag-gated MFMA tile (all-dataflow phase A; no grid.sync).
__device__ __forceinline__ void tile_mfma(
    int sbase, int B, int i,
    const int* __restrict__ bArr, const int* __restrict__ pArr,
    const unsigned short* __restrict__ UBz, const unsigned short* __restrict__ UBr,
    const unsigned short* __restrict__ UBh,
    const float* __restrict__ XPz, const float* __restrict__ XPr, const float* __restrict__ XPh,
    float* __restrict__ out, const int* __restrict__ order,
    const int* __restrict__ pred, int* __restrict__ flagArr,
    float* pool, int* tj, int* rbs, int* rps)
{
    unsigned short* Hbf  = (unsigned short*)(pool + 8192);
    unsigned short* RHbf = (unsigned short*)(pool + 12288);
    unsigned* H32 = (unsigned*)Hbf;
    const short8* BzF = (const short8*)UBz;
    const short8* BrF = (const short8*)UBr;
    const short8* BhF = (const short8*)UBh;
    const short8* AF  = (const short8*)Hbf;
    const short8* RF  = (const short8*)RHbf;
    const int lane = i & 63;
    const int w = i >> 6;

    __syncthreads();                       // guard LDS reuse
    if (i < 16) {
        int t = (i < B) ? order[sbase + i] : -1;
        if (t >= 0) {
            int p0 = pred[2 * t], p1 = pred[2 * t + 1];
            while (p0 >= 0 && __hip_atomic_load(&flagArr[p0], __ATOMIC_ACQUIRE,
                                                __HIP_MEMORY_SCOPE_AGENT) < NSLICE)
                __builtin_amdgcn_s_sleep(2);
            while (p1 >= 0 && __hip_atomic_load(&flagArr[p1], __ATOMIC_ACQUIRE,
                                                __HIP_MEMORY_SCOPE_AGENT) < NSLICE)
                __builtin_amdgcn_s_sleep(2);
        }
        tj[i] = t;
        rbs[i] = (t >= 0) ? bArr[t] : 0;
        rps[i] = (t >= 0) ? pArr[t] : 0;
    }
    __syncthreads();

    // gather h -> Hs (f32) + Hbf (bf16 A-fragment layout); LLC loads
    for (int idx2 = i; idx2 < 16 * 256; idx2 += 512) {
        int j = idx2 >> 8, kp = (idx2 & 255) << 1;    // kp even
        float v0 = 0.0f, v1 = 0.0f;
        if (tj[j] >= 0) {
            int row = (kp < SS) ? rbs[j] : rps[j];
            const float* rowp = out + row * SS + (kp & (SS - 1));
            v0 = loadLLC_(rowp);
            v1 = loadLLC_(rowp + 1);
        }
        pool[j * S2 + kp] = v0;
        pool[j * S2 + kp + 1] = v1;
        int ks = kp >> 5, kk = kp & 31;
        H32[((((ks << 6) + j + ((kk >> 3) << 4)) << 3) + (kk & 7)) >> 1] = pk2_(v0, v1);
    }
    __syncthreads();

    // prefetch XPz/XPr
    f32x4 xpz[4], xpr[4];
#pragma unroll
    for (int nb2 = 0; nb2 < 4; ++nb2) {
        int c = (w * 4 + nb2) * 16 + (lane & 15);
#pragma unroll
        for (int q = 0; q < 4; ++q) {
            int m = ((lane >> 4) << 2) + q;
            int t = tj[m];
            xpz[nb2][q] = (t >= 0) ? XPz[t * S2 + c] : 0.f;
            xpr[nb2][q] = (t >= 0) ? XPr[t * S2 + c] : 0.f;
        }
    }

    // ---- z/r MFMA pass ----
    f32x4 accz[4], accr[4];
#pragma unroll
    for (int nb2 = 0; nb2 < 4; ++nb2) {
        accz[nb2] = (f32x4){0.f, 0.f, 0.f, 0.f};
        accr[nb2] = (f32x4){0.f, 0.f, 0.f, 0.f};
    }
#pragma unroll 1
    for (int ks = 0; ks < 16; ++ks) {
        short8 a = AF[(ks << 6) + lane];
#pragma unroll
        for (int nb2 = 0; nb2 < 4; ++nb2) {
            int nb = w * 4 + nb2;
            short8 bz = BzF[((nb << 4) + ks) * 64 + lane];
            short8 br = BrF[((nb << 4) + ks) * 64 + lane];
            accz[nb2] = __builtin_amdgcn_mfma_f32_16x16x32_bf16(a, bz, accz[nb2], 0, 0, 0);
            accr[nb2] = __builtin_amdgcn_mfma_f32_16x16x32_bf16(a, br, accr[nb2], 0, 0, 0);
        }
    }
    // epilogue 1: activations, write RHbf
    f32x4 zv[4];
#pragma unroll
    for (int nb2 = 0; nb2 < 4; ++nb2) {
        int c = (w * 4 + nb2) * 16 + (lane & 15);
#pragma unroll
        for (int q = 0; q < 4; ++q) {
            int m = ((lane >> 4) << 2) + q;
            int t = tj[m];
            float h = pool[m * S2 + c];
            float zpre = accz[nb2][q] + xpz[nb2][q] + DIAG * h;
            float rpre = accr[nb2][q] + xpr[nb2][q] + DIAG * h;
            zv[nb2][q] = sigmoidf_(zpre);
            float rh = (t >= 0) ? sigmoidf_(rpre) * h : 0.f;
            int ks = c >> 5, kk = c & 31;
            RHbf[((ks << 6) + m + ((kk >> 3) << 4)) * 8 + (kk & 7)] = f2bf_(rh);
        }
    }
    __syncthreads();                        // RHbf ready

    // prefetch XPh
    f32x4 xph[4];
#pragma unroll
    for (int nb2 = 0; nb2 < 4; ++nb2) {
        int c = (w * 4 + nb2) * 16 + (lane & 15);
#pragma unroll
        for (int q = 0; q < 4; ++q) {
            int m = ((lane >> 4) << 2) + q;
            int t = tj[m];
            xph[nb2][q] = (t >= 0) ? XPh[t * S2 + c] : 0.f;
        }
    }

    // ---- m MFMA pass ----
    f32x4 accm[4];
#pragma unroll
    for (int nb2 = 0; nb2 < 4; ++nb2) accm[nb2] = (f32x4){0.f, 0.f, 0.f, 0.f};
#pragma unroll 1
    for (int ks = 0; ks < 16; ++ks) {
        short8 a = RF[(ks << 6) + lane];
#pragma unroll
        for (int nb2 = 0; nb2 < 4; ++nb2) {
            int nb = w * 4 + nb2;
            short8 bh = BhF[((nb << 4) + ks) * 64 + lane];
            accm[nb2] = __builtin_amdgcn_mfma_f32_16x16x32_bf16(a, bh, accm[nb2], 0, 0, 0);
        }
    }
    // epilogue 2: hn, scatter (LLC stores), then release step flags
#pragma unroll
    for (int nb2 = 0; nb2 < 4; ++nb2) {
        int c = (w * 4 + nb2) * 16 + (lane & 15);
#pragma unroll
        for (int q = 0; q < 4; ++q) {
            int m = ((lane >> 4) << 2) + q;
            int t = tj[m];
            if (t >= 0) {
                float h = pool[m * S2 + c];
                int ks = c >> 5, kk = c & 31;
                float rh = __uint_as_float(
                    ((unsigned)RHbf[((ks << 6) + m + ((kk >> 3) << 4)) * 8 + (kk & 7)]) << 16);
                float mm = tanhf(accm[nb2][q] + xph[nb2][q] + DIAG * rh);
                float z = zv[nb2][q];
                float hn = z * h + (1.f - z) * mm;
                int rb = rbs[m], rp = rps[m];
                int row = (c < SS) ? rb : rp;
                float* addr = out + row * SS + (c & (SS - 1));
                if (rb == rp) atomicAdd(addr, hn - h);
                else storeLLC_(addr, hn);
            }
        }
    }
    __syncthreads();                        // all stores drained (vmcnt before barrier)
    if (i < 16 && tj[i] >= 0)
        __hip_atomic_store(&flagArr[tj[i]], NSLICE, __ATOMIC_RELEASE,
                           __HIP_MEMORY_SCOPE_AGENT);
}

// VALU fallback tile body (only used when !useXP) — barrier-based.
template<int BQ>
__device__ __forceinline__ void process_level_valu(
    int s0, int s1, int i,
    const float* __restrict__ x,
    const int* __restrict__ bArr, const int* __restrict__ pArr,
    const float4* __restrict__ Wz4, const float4* __restrict__ Wr4, const float4* __restrict__ Wh4,
    const uint4* __restrict__ Uzr, const uint2* __restrict__ Uhp,
    float bzi, float bri, float bhi,
    float* __restrict__ out, const int* __restrict__ order,
    float* pool, int* tj, int* rbs, int* rps)
{
    float* Hsf = pool;
    float* RHf = pool + 8192;
    float* xsf = pool + 16384;
    const int nT = (s1 - s0 + BQ - 1) / BQ;
    for (int tile = blockIdx.x; tile < nT; tile += gridDim.x) {
        const int sbase = s0 + tile * BQ;
        const int B = (sbase + BQ <= s1) ? BQ : (s1 - sbase);
        __syncthreads();
        if (i < BQ) {
            int t = (i < B) ? order[sbase + i] : -1;
            tj[i] = t;
            rbs[i] = (t >= 0) ? bArr[t] : 0;
            rps[i] = (t >= 0) ? pArr[t] : 0;
        }
        __syncthreads();
        for (int idx = i; idx < BQ * S2; idx += 512) {
            int j = idx >> 9, k = idx & (S2 - 1);
            float v = 0.0f;
            if (tj[j] >= 0) {
                int row = (k < SS) ? rbs[j] : rps[j];
                v = out[row * SS + (k & (SS - 1))];
            }
            Hsf[j * S2 + k] = v;
        }
        for (int idx = i; idx < BQ * SIT; idx += 512) {
            int j = idx >> 6, k = idx & (SIT - 1);
            int t = tj[j];
            xsf[j * SIT + k] = (t >= 0) ? x[t * SIT + k] : 0.0f;
        }
        float zacc[BQ], racc[BQ];
#pragma unroll
        for (int j = 0; j < BQ; ++j) { zacc[j] = 0.0f; racc[j] = 0.0f; }
        __syncthreads();
        for (int kb = 0; kb < WKB; ++kb) {
            float4 a4 = Wz4[kb * S2 + i];
            float4 b4 = Wr4[kb * S2 + i];
#pragma unroll
            for (int j = 0; j < BQ; ++j) {
                float4 x4 = *(const float4*)(&xsf[j * SIT + kb * 4]);
                zacc[j] += dot4_(a4, x4);
                racc[j] += dot4_(b4, x4);
            }
        }
        for (int kb = 0; kb < NKB; ++kb) {
            uint4 u = Uzr[kb * S2 + i];
#pragma unroll
            for (int j = 0; j < BQ; ++j) {
                float4 h4 = *(const float4*)(&Hsf[j * S2 + kb * 4]);
                zacc[j] += bflo_(u.x) * h4.x + bfhi_(u.x) * h4.y + bflo_(u.y) * h4.z + bfhi_(u.y) * h4.w;
                racc[j] += bflo_(u.z) * h4.x + bfhi_(u.z) * h4.y + bflo_(u.w) * h4.z + bfhi_(u.w) * h4.w;
            }
        }
        float zv[BQ];
#pragma unroll
        for (int j = 0; j < BQ; ++j) {
            float hOwn = Hsf[j * S2 + i];
            zv[j] = sigmoidf_(zacc[j] + DIAG * hOwn + bzi);
            RHf[j * S2 + i] = sigmoidf_(racc[j] + DIAG * hOwn - bri) * hOwn;
        }
        __syncthreads();
        float macc[BQ];
#pragma unroll
        for (int j = 0; j < BQ; ++j) macc[j] = 0.0f;
        for (int kb = 0; kb < WKB; ++kb) {
            float4 a4 = Wh4[kb * S2 + i];
#pragma unroll
            for (int j = 0; j < BQ; ++j) {
                float4 x4 = *(const float4*)(&xsf[j * SIT + kb * 4]);
                macc[j] += dot4_(a4, x4);
            }
        }
        for (int kb = 0; kb < NKB; ++kb) {
            uint2 u = Uhp[kb * S2 + i];
#pragma unroll
            for (int j = 0; j < BQ; ++j) {
                float4 h4 = *(const float4*)(&RHf[j * S2 + kb * 4]);
                macc[j] += bflo_(u.x) * h4.x + bfhi_(u.x) * h4.y + bflo_(u.y) * h4.z + bfhi_(u.y) * h4.w;
            }
        }
        for (int j = 0; j < B; ++j) {
            float mm = tanhf(macc[j] + DIAG * RHf[j * S2 + i] + bhi);
            float h = Hsf[j * S2 + i];
            float hn = zv[j] * h + (1.0f - zv[j]) * mm;
            int rb = rbs[j], rp = rps[j];
            int row = (i < SS) ? rb : rp;
            float* addr = out + row * SS + (i & (SS - 1));
            if (rb == rp) atomicAdd(addr, hn - h);
            else *addr = hn;
        }
    }
}

__global__ __launch_bounds__(512, 4) void k_main(
    const float* __restrict__ x, const int* __restrict__ bArr, const int* __restrict__ pArr,
    const float* __restrict__ WzT, const float* __restrict__ WrT, const float* __restrict__ WhT,
    const uint4* __restrict__ Uzr, const uint2* __restrict__ Uhp,
    const unsigned short* __restrict__ UBz, const unsigned short* __restrict__ UBr,
    const unsigned short* __restrict__ UBh,
    const float* __restrict__ bz, const float* __restrict__ br, const float* __restrict__ bh,
    float* __restrict__ out,
    const int* __restrict__ order, const int* __restrict__ levelStart,
    const int* __restrict__ numLevels,
    const float* __restrict__ XPz, const float* __restrict__ XPr, const float* __restrict__ XPh,
    const int* __restrict__ pred, int* __restrict__ flagArr,
    int* __restrict__ rhCnt, float* __restrict__ RHstage,
    int useXP, int useSlice)
{
    cg::grid_group grid = cg::this_grid();
    __shared__ float pool[17408];
    __shared__ int tj[BQMAX], rbs[BQMAX], rps[BQMAX];

    const int i = threadIdx.x;
    const float bzi = bz[i], bri = br[i], bhi = bh[i];
    const float4* Wz4 = (const float4*)WzT;
    const float4* Wr4 = (const float4*)WrT;
    const float4* Wh4 = (const float4*)WhT;

    const int cutoff = numLevels[1];
    const int sB = levelStart[cutoff];
    const int nB = T_STEPS - sB;

    // ---- phase A ----
    if (useXP) {
        // all-dataflow: flag-gated tiles, no grid.sync (flags pre-zeroed by host memset)
        for (int lvl = 1; lvl <= cutoff; ++lvl) {
            const int s0 = levelStart[lvl - 1], s1 = levelStart[lvl];
            const int nT = (s1 - s0 + 15) / 16;
            for (int tile = blockIdx.x; tile < nT; tile += gridDim.x) {
                const int sbase = s0 + tile * 16;
                const int B = (sbase + 16 <= s1) ? 16 : (s1 - sbase);
                tile_mfma(sbase, B, i, bArr, pArr, UBz, UBr, UBh,
                          XPz, XPr, XPh, out, order, pred, flagArr,
                          pool, tj, rbs, rps);
            }
        }
    } else {
        for (int lvl = 1; lvl <= cutoff; ++lvl) {
            const int s0 = levelStart[lvl - 1], s1 = levelStart[lvl];
            process_level_valu<8>(s0, s1, i, x, bArr, pArr, Wz4, Wr4, Wh4,
                                  Uzr, Uhp, bzi, bri, bhi, out, order,
                                  pool, tj, rbs, rps);
            grid.sync();
        }
        for (int s = blockIdx.x * 512 + i; s < T_STEPS; s += gridDim.x * 512)
            if (s < sB) flagArr[order[s]] = NSLICE;
        grid.sync();
    }

    float* Hs0 = pool;
    float* PB1 = pool + 8192;
    float* PB2 = pool + 8704;
    float* PB3 = pool + 9216;
    float* RHs0 = pool + 9728;
    float* xs0 = pool + 16384;

    if (useSlice && nB <= MAXB) {
        // ---- phase B (sliced): 4 blocks per step ----
        const int jr = i & 127;
        const int ks = i >> 7;
        for (int g = blockIdx.x; g < NSLICE * nB; g += gridDim.x) {
            const int s = sB + (g >> 2);
            const int q = g & 3;
            const int t = order[s];
            const int slot = s - sB;
            if (i == 0) {
                int p0 = pred[2 * t], p1 = pred[2 * t + 1];
                while (p0 >= 0 && __hip_atomic_load(&flagArr[p0], __ATOMIC_ACQUIRE,
                                                    __HIP_MEMORY_SCOPE_AGENT) < NSLICE)
                    __builtin_amdgcn_s_sleep(2);
                while (p1 >= 0 && __hip_atomic_load(&flagArr[p1], __ATOMIC_ACQUIRE,
                                                    __HIP_MEMORY_SCOPE_AGENT) < NSLICE)
                    __builtin_amdgcn_s_sleep(2);
            }
            __syncthreads();

            const int rb = bArr[t], rp = pArr[t];
            {
                const int row = (i < SS) ? rb : rp;
                Hs0[i] = loadLLC_(out + row * SS + (i & (SS - 1)));
            }
            __syncthreads();

            const int myrow = q * 128 + jr;
            const int kb0 = ks * 32;
            float zp = 0.f, rpv = 0.f;
            for (int kb = kb0; kb < kb0 + 32; ++kb) {
                uint4 u = Uzr[kb * S2 + myrow];
                float4 h4 = *(const float4*)(&Hs0[kb * 4]);
                zp  += bflo_(u.x) * h4.x + bfhi_(u.x) * h4.y + bflo_(u.y) * h4.z + bfhi_(u.y) * h4.w;
                rpv += bflo_(u.z) * h4.x + bfhi_(u.z) * h4.y + bflo_(u.w) * h4.z + bfhi_(u.w) * h4.w;
            }
            PB1[ks * 128 + jr] = zp;
            PB2[ks * 128 + jr] = rpv;
            __syncthreads();
            if (i < 128) {
                float hOwn = Hs0[q * 128 + i];
                float zsum = XPz[t * S2 + q * 128 + i] + DIAG * hOwn
                           + PB1[i] + PB1[128 + i] + PB1[256 + i] + PB1[384 + i];
                float rsum = XPr[t * S2 + q * 128 + i] + DIAG * hOwn
                           + PB2[i] + PB2[128 + i] + PB2[256 + i] + PB2[384 + i];
                float zvv = sigmoidf_(zsum);
                float rh = sigmoidf_(rsum) * hOwn;
                storeLLC_(RHstage + (size_t)slot * S2 + q * 128 + i, rh);
                PB3[i] = zvv;
            }
            __syncthreads();
            if (i == 0) {
                __hip_atomic_fetch_add(&rhCnt[slot], 1, __ATOMIC_RELEASE,
                                       __HIP_MEMORY_SCOPE_AGENT);
                while (__hip_atomic_load(&rhCnt[slot], __ATOMIC_ACQUIRE,
                                         __HIP_MEMORY_SCOPE_AGENT) < NSLICE)
                    __builtin_amdgcn_s_sleep(1);
            }
            __syncthreads();
            RHs0[i] = loadLLC_(RHstage + (size_t)slot * S2 + i);
            __syncthreads();

            float mp = 0.f;
            for (int kb = kb0; kb < kb0 + 32; ++kb) {
                uint2 u = Uhp[kb * S2 + myrow];
                float4 h4 = *(const float4*)(&RHs0[kb * 4]);
                mp += bflo_(u.x) * h4.x + bfhi_(u.x) * h4.y + bflo_(u.y) * h4.z + bfhi_(u.y) * h4.w;
            }
            PB1[ks * 128 + jr] = mp;
            __syncthreads();
            if (i < 128) {
                float msum = XPh[t * S2 + q * 128 + i] + DIAG * RHs0[q * 128 + i]
                           + PB1[i] + PB1[128 + i] + PB1[256 + i] + PB1[384 + i];
                float mm = tanhf(msum);
                float zz = PB3[i];
                float h0 = Hs0[q * 128 + i];
                float hn = zz * h0 + (1.f - zz) * mm;
                int grow = q * 128 + i;
                int orow = (grow < SS) ? rb : rp;
                float* addr = out + orow * SS + (grow & (SS - 1));
                if (rb == rp) atomicAdd(addr, hn - h0);
                else storeLLC_(addr, hn);
            }
            __syncthreads();
            if (i == 0)
                __hip_atomic_fetch_add(&flagArr[t], 1, __ATOMIC_RELEASE,
                                       __HIP_MEMORY_SCOPE_AGENT);
        }
    } else {
        // ---- phase B fallback: one block per step ----
        for (int s = sB + blockIdx.x; s < T_STEPS; s += gridDim.x) {
            const int t = order[s];
            if (i == 0) {
                int p0 = pred[2 * t], p1 = pred[2 * t + 1];
                while (p0 >= 0 && __hip_atomic_load(&flagArr[p0], __ATOMIC_ACQUIRE,
                                                    __HIP_MEMORY_SCOPE_AGENT) < NSLICE)
                    __builtin_amdgcn_s_sleep(2);
                while (p1 >= 0 && __hip_atomic_load(&flagArr[p1], __ATOMIC_ACQUIRE,
                                                    __HIP_MEMORY_SCOPE_AGENT) < NSLICE)
                    __builtin_amdgcn_s_sleep(2);
            }
            __syncthreads();

            const int rb = bArr[t], rp = pArr[t];
            const int row = (i < SS) ? rb : rp;
            float* addr = out + row * SS + (i & (SS - 1));
            const float h = loadLLC_(addr);
            Hs0[i] = h;
            float zacc, racc;
            if (useXP) {
                zacc = XPz[t * S2 + i];
                racc = XPr[t * S2 + i];
            } else {
                zacc = 0.0f; racc = 0.0f;
                if (i < SIT) xs0[i] = x[t * SIT + i];
            }
            __syncthreads();

            if (!useXP) {
                for (int kb = 0; kb < WKB; ++kb) {
                    float4 a4 = Wz4[kb * S2 + i];
                    float4 b4 = Wr4[kb * S2 + i];
                    float4 x4 = *(const float4*)(&xs0[kb * 4]);
                    zacc += dot4_(a4, x4);
                    racc += dot4_(b4, x4);
                }
            }
            for (int kb = 0; kb < NKB; ++kb) {
                uint4 u = Uzr[kb * S2 + i];
                float4 h4 = *(const float4*)(&Hs0[kb * 4]);
                zacc += bflo_(u.x) * h4.x + bfhi_(u.x) * h4.y + bflo_(u.y) * h4.z + bfhi_(u.y) * h4.w;
                racc += bflo_(u.z) * h4.x + bfhi_(u.z) * h4.y + bflo_(u.w) * h4.z + bfhi_(u.w) * h4.w;
            }
            const float zvv = sigmoidf_(zacc + DIAG * h + (useXP ? 0.f : bzi));
            const float rv = sigmoidf_(racc + DIAG * h - (useXP ? 0.f : bri));
            RHs0[i] = rv * h;
            __syncthreads();

            float macc;
            if (useXP) {
                macc = XPh[t * S2 + i];
            } else {
                macc = 0.0f;
                for (int kb = 0; kb < WKB; ++kb) {
                    float4 a4 = Wh4[kb * S2 + i];
                    float4 x4 = *(const float4*)(&xs0[kb * 4]);
                    macc += dot4_(a4, x4);
                }
            }
            for (int kb = 0; kb < NKB; ++kb) {
                uint2 u = Uhp[kb * S2 + i];
                float4 h4 = *(const float4*)(&RHs0[kb * 4]);
                macc += bflo_(u.x) * h4.x + bfhi_(u.x) * h4.y + bflo_(u.y) * h4.z + bfhi_(u.y) * h4.w;
            }
            const float mm = tanhf(macc + DIAG * RHs0[i] + (useXP ? 0.f : bhi));
            const float hn = zvv * h + (1.0f - zvv) * mm;
            if (rb == rp) atomicAdd(addr, hn - h);
            else storeLLC_(addr, hn);
            __syncthreads();
            if (i == 0)
                __hip_atomic_fetch_add(&flagArr[t], NSLICE, __ATOMIC_RELEASE,
                                       __HIP_MEMORY_SCOPE_AGENT);
        }
    }
}

// ---------------- host launcher ----------------

extern "C" void kernel_launch(void* const* d_in, const int* in_sizes, int n_in,
                              void* d_out, int out_size, void* d_ws, size_t ws_size,
                              hipStream_t stream) {
    const float* x  = (const float*)d_in[0];
    const int*   b  = (const int*)d_in[1];
    const int*   p  = (const int*)d_in[2];
    const float* Wz = (const float*)d_in[3];
    const float* Wr = (const float*)d_in[4];
    const float* Wh = (const float*)d_in[5];
    const float* Uz = (const float*)d_in[6];
    const float* Ur = (const float*)d_in[7];
    const float* Uh = (const float*)d_in[8];
    const float* bz = (const float*)d_in[9];
    const float* br = (const float*)d_in[10];
    const float* bh = (const float*)d_in[11];
    const float* table0 = (const float*)d_in[12];
    float* out = (float*)d_out;

    float* base = (float*)d_ws;
    uint4* UzrP = (uint4*)base;
    uint2* UhP  = (uint2*)(base + 262144);
    unsigned short* UBz = (unsigned short*)(base + 262144 + 131072);
    unsigned short* UBr = (unsigned short*)(base + 262144 + 2 * 131072);
    unsigned short* UBh = (unsigned short*)(base + 262144 + 3 * 131072);
    float* WzT  = base + 262144 + 4 * 131072;
    float* WrT  = WzT + S2 * SIT;
    float* WhT  = WrT + S2 * SIT;
    int* cnt = (int*)(WhT + S2 * SIT);
    int* cur = cnt + NPL;
    int* bas = cur + NPL;
    int* list = bas + NPL;
    int* pred = list + NEV;
    int* order = pred + NEV;
    int* levelStart = order + T_STEPS;
    int* numLevels = levelStart + 260;
    int* flagArr = numLevels + 4;
    int* rhCnt = flagArr + T_STEPS;

    size_t baseFloats = (size_t)262144 + 4 * 131072 + 3 * S2 * SIT
                      + 3 * NPL + 2 * NEV + T_STEPS + 264 + T_STEPS + MAXB;
    baseFloats = (baseFloats + 255) & ~(size_t)255;
    float* RHstage = base + baseFloats;
    size_t rhFloats = (size_t)MAXB * S2;
    size_t xpFloats = 3ull * T_STEPS * S2;

    int useSlice = 0, useXP = 0;
    float *XPz;
    if (ws_size >= (baseFloats + rhFloats + xpFloats) * 4ull) {
        useSlice = 1; useXP = 1; XPz = RHstage + rhFloats;
    } else if (ws_size >= (baseFloats + xpFloats) * 4ull) {
        useXP = 1; XPz = RHstage;
    } else {
        XPz = RHstage;
    }
    float* XPr = XPz + (size_t)T_STEPS * S2;
    float* XPh = XPr + (size_t)T_STEPS * S2;

    hipMemsetAsync(cnt, 0, NPL * sizeof(int), stream);
    hipMemsetAsync(flagArr, 0, (T_STEPS + MAXB) * sizeof(int), stream);
    hipLaunchKernelGGL(k_trans, dim3(1024, 8), dim3(256), 0, stream,
                       Uz, Ur, Uh, Wz, Wr, Wh, UzrP, UhP, UBz, UBr, UBh, WzT, WrT, WhT);
    hipLaunchKernelGGL(k_count, dim3((NEV + 255) / 256), dim3(256), 0, stream, b, p, cnt);
    hipLaunchKernelGGL(k_scan, dim3(1), dim3(1024), 0, stream, cnt, bas, cur);
    hipLaunchKernelGGL(k_place, dim3((NEV + 255) / 256), dim3(256), 0, stream, b, p, cur, list);
    hipLaunchKernelGGL(k_pred, dim3((NPL + 255) / 256), dim3(256), 0, stream, bas, cnt, list, pred);
    hipLaunchKernelGGL(k_levels, dim3(1), dim3(1024), 0, stream,
                       pred, order, levelStart, numLevels);

    int n4 = NPL * SS / 4;
    hipLaunchKernelGGL(k_copy, dim3((n4 + 255) / 256), dim3(256), 0, stream,
                       (const float4*)table0, (float4*)out, n4);
    if (useXP) {
        hipLaunchKernelGGL(k_xp, dim3(T_STEPS / 16), dim3(512), 0, stream,
                           x, WzT, WrT, WhT, bz, br, bh, XPz, XPr, XPh);
    }

    int occ = 0;
    if (hipOccupancyMaxActiveBlocksPerMultiprocessor(&occ, k_main, 512, 0) != hipSuccess)
        occ = 1;
    if (occ < 1) occ = 1;
    if (occ > 2) occ = 2;
    int gridSz = occ * 256;

    void* args[] = {
        (void*)&x, (void*)&b, (void*)&p,
        (void*)&WzT, (void*)&WrT, (void*)&WhT,
        (void*)&UzrP, (void*)&UhP,
        (void*)&UBz, (void*)&UBr, (void*)&UBh,
        (void*)&bz, (void*)&br, (void*)&bh,
        (void*)&out,
        (void*)&order, (void*)&levelStart, (void*)&numLevels,
        (void*)&XPz, (void*)&XPr, (void*)&XPh,
        (void*)&pred, (void*)&flagArr, (void*)&rhCnt, (void*)&RHstage,
        (void*)&useXP, (void*)&useSlice
    };
    hipError_t e = hipLaunchCooperativeKernel((void*)k_main, dim3(gridSz), dim3(512), args, 0, stream);
    if (e != hipSuccess && gridSz != 256) {
        hipLaunchCooperativeKernel((void*)k_main, dim3(256), dim3(512), args, 0, stream);
    }
}

// Round 18
// 637.861 us; speedup vs baseline: 1.9598x; 1.9598x over previous
//
#include <hip/hip_runtime.h>
#include <hip/hip_cooperative_groups.h>

namespace cg = cooperative_groups;

#define T_STEPS 8192
#define SIT     64
#define SS      256
#define S2      512
#define NPL     32000
#define NEV     (2*T_STEPS)
#define MAXLEV  255
#define RELAX   48
#define NKB     (S2/4)
#define WKB     (SIT/4)
#define BQMAX   16
#define CUTN    300
#define NSLICE  4
#define MAXB    4096
#define DIAG    0.8f

typedef __attribute__((ext_vector_type(8))) short short8;
typedef __attribute__((ext_vector_type(4))) float f32x4;

__device__ __forceinline__ float sigmoidf_(float x) {
    return 1.0f / (1.0f + expf(-x));
}
__device__ __forceinline__ float bflo_(unsigned u) { return __uint_as_float(u << 16); }
__device__ __forceinline__ float bfhi_(unsigned u) { return __uint_as_float(u & 0xFFFF0000u); }
__device__ __forceinline__ unsigned short f2bf_(float f) {
    unsigned u = __float_as_uint(f);
    u = u + 0x7FFFu + ((u >> 16) & 1u);
    return (unsigned short)(u >> 16);
}
__device__ __forceinline__ unsigned pk2_(float a, float b) {
    return (unsigned)f2bf_(a) | ((unsigned)f2bf_(b) << 16);
}
__device__ __forceinline__ float dot4_(float4 a, float4 b) {
    return a.x*b.x + a.y*b.y + a.z*b.z + a.w*b.w;
}
__device__ __forceinline__ float loadLLC_(const float* p) {
    return __hip_atomic_load(p, __ATOMIC_RELAXED, __HIP_MEMORY_SCOPE_AGENT);
}
__device__ __forceinline__ void storeLLC_(float* p, float v) {
    __hip_atomic_store(p, v, __ATOMIC_RELAXED, __HIP_MEMORY_SCOPE_AGENT);
}

// ---------------- preprocessing kernels ----------------

__global__ void k_count(const int* __restrict__ b, const int* __restrict__ p, int* cnt) {
    int e = blockIdx.x * blockDim.x + threadIdx.x;
    if (e < NEV) {
        int v = (e & 1) ? p[e >> 1] : b[e >> 1];
        atomicAdd(&cnt[v], 1);
    }
}

__global__ __launch_bounds__(1024) void k_scan(const int* __restrict__ cnt, int* bas, int* cur) {
    __shared__ int partial[1024];
    int tid = threadIdx.x;
    int start = tid * 32;
    int end = start + 32; if (end > NPL) end = NPL;
    int s = 0;
    for (int i = start; i < end; ++i) s += cnt[i];
    partial[tid] = s;
    __syncthreads();
    for (int off = 1; off < 1024; off <<= 1) {
        int v = partial[tid];
        int add = (tid >= off) ? partial[tid - off] : 0;
        __syncthreads();
        partial[tid] = v + add;
        __syncthreads();
    }
    int acc = (tid == 0) ? 0 : partial[tid - 1];
    for (int i = start; i < end; ++i) {
        bas[i] = acc; cur[i] = acc; acc += cnt[i];
    }
}

__global__ void k_place(const int* __restrict__ b, const int* __restrict__ p, int* cur, int* list) {
    int e = blockIdx.x * blockDim.x + threadIdx.x;
    if (e < NEV) {
        int v = (e & 1) ? p[e >> 1] : b[e >> 1];
        int pos = atomicAdd(&cur[v], 1);
        list[pos] = e;
    }
}

__global__ void k_pred(const int* __restrict__ bas, const int* __restrict__ cnt, int* list, int* pred) {
    int v = blockIdx.x * blockDim.x + threadIdx.x;
    if (v >= NPL) return;
    int s0 = bas[v], c = cnt[v];
    for (int i2 = 1; i2 < c; ++i2) {
        int key = list[s0 + i2];
        int j = i2 - 1;
        while (j >= 0 && list[s0 + j] > key) { list[s0 + j + 1] = list[s0 + j]; --j; }
        list[s0 + j + 1] = key;
    }
    int prevS = -1, curS = -1;
    for (int i2 = 0; i2 < c; ++i2) {
        int e = list[s0 + i2];
        int s = e >> 1;
        if (s != curS) { prevS = curS; curS = s; }
        pred[e] = prevS;
    }
}

__global__ __launch_bounds__(1024) void k_levels(const int* __restrict__ pred,
                                                 int* order, int* levelStart, int* numLevels) {
    __shared__ short p0[T_STEPS], p1[T_STEPS];
    __shared__ unsigned char lev[T_STEPS];
    __shared__ int cnts[MAXLEV + 2];
    __shared__ int maxLev;
    __shared__ int changed;
    int tid = threadIdx.x;
    for (int t = tid; t < T_STEPS; t += 1024) {
        p0[t] = (short)pred[2 * t];
        p1[t] = (short)pred[2 * t + 1];
        lev[t] = 1;
    }
    for (int l = tid; l < MAXLEV + 2; l += 1024) cnts[l] = 0;
    if (tid == 0) maxLev = 0;
    __syncthreads();
    for (int r = 0; r < RELAX; ++r) {
        if (tid == 0) changed = 0;
        __syncthreads();
        for (int t = tid; t < T_STEPS; t += 1024) {
            int a = p0[t], b2 = p1[t];
            int la = (a >= 0) ? (int)lev[a] : 0;
            int lb = (b2 >= 0) ? (int)lev[b2] : 0;
            int nl = 1 + (la > lb ? la : lb);
            if (nl > MAXLEV) nl = MAXLEV;
            if (nl > (int)lev[t]) { lev[t] = (unsigned char)nl; changed = 1; }
        }
        __syncthreads();
        int ch = changed;
        __syncthreads();
        if (!ch) break;
    }
    for (int t = tid; t < T_STEPS; t += 1024) {
        atomicAdd(&cnts[lev[t]], 1);
        atomicMax(&maxLev, (int)lev[t]);
    }
    __syncthreads();
    if (tid == 0) {
        int acc = 0;
        levelStart[0] = 0;
        int cut = 0, stopped = 0;
        for (int l = 1; l <= maxLev; ++l) {
            int c = cnts[l];
            if (!stopped) { if (c > CUTN) cut = l; else stopped = 1; }
            cnts[l] = acc;
            acc += c;
            levelStart[l] = acc;
        }
        numLevels[0] = maxLev;
        numLevels[1] = cut;
    }
    __syncthreads();
    for (int t = tid; t < T_STEPS; t += 1024) {
        int pos = atomicAdd(&cnts[lev[t]], 1);
        order[pos] = t;
    }
}

// transpose/compress: Uzr/Uhp row-packed bf16 (phase B), UB* MFMA B-fragment
// order (phase A), W transposed f32. V = U - DIAG*I everywhere.
__global__ void k_trans(const float* __restrict__ Uz, const float* __restrict__ Ur,
                        const float* __restrict__ Uh, const float* __restrict__ Wz,
                        const float* __restrict__ Wr, const float* __restrict__ Wh,
                        uint4* __restrict__ UzrP, uint2* __restrict__ UhP,
                        unsigned short* __restrict__ UBz, unsigned short* __restrict__ UBr,
                        unsigned short* __restrict__ UBh,
                        float* WzT, float* WrT, float* WhT) {
    int y = blockIdx.y;
    int idx = blockIdx.x * blockDim.x + threadIdx.x;
    if (y == 0) {
        if (idx < S2 * NKB) {
            int kb = idx >> 9, i2 = idx & (S2 - 1);
            int k = kb * 4;
            float z0 = Uz[i2 * S2 + k + 0] - ((i2 == k + 0) ? DIAG : 0.f);
            float z1 = Uz[i2 * S2 + k + 1] - ((i2 == k + 1) ? DIAG : 0.f);
            float z2 = Uz[i2 * S2 + k + 2] - ((i2 == k + 2) ? DIAG : 0.f);
            float z3 = Uz[i2 * S2 + k + 3] - ((i2 == k + 3) ? DIAG : 0.f);
            float r0 = Ur[i2 * S2 + k + 0] - ((i2 == k + 0) ? DIAG : 0.f);
            float r1 = Ur[i2 * S2 + k + 1] - ((i2 == k + 1) ? DIAG : 0.f);
            float r2 = Ur[i2 * S2 + k + 2] - ((i2 == k + 2) ? DIAG : 0.f);
            float r3 = Ur[i2 * S2 + k + 3] - ((i2 == k + 3) ? DIAG : 0.f);
            uint4 o;
            o.x = pk2_(z0, z1); o.y = pk2_(z2, z3);
            o.z = pk2_(r0, r1); o.w = pk2_(r2, r3);
            UzrP[idx] = o;
        }
    } else if (y == 1) {
        if (idx < S2 * NKB) {
            int kb = idx >> 9, i2 = idx & (S2 - 1);
            int k = kb * 4;
            float h0 = Uh[i2 * S2 + k + 0] - ((i2 == k + 0) ? DIAG : 0.f);
            float h1 = Uh[i2 * S2 + k + 1] - ((i2 == k + 1) ? DIAG : 0.f);
            float h2 = Uh[i2 * S2 + k + 2] - ((i2 == k + 2) ? DIAG : 0.f);
            float h3 = Uh[i2 * S2 + k + 3] - ((i2 == k + 3) ? DIAG : 0.f);
            uint2 o;
            o.x = pk2_(h0, h1); o.y = pk2_(h2, h3);
            UhP[idx] = o;
        }
    } else if (y <= 4) {
        const float* S = (y == 2) ? Wz : (y == 3) ? Wr : Wh;
        float*       D = (y == 2) ? WzT : (y == 3) ? WrT : WhT;
        if (idx < S2 * SIT) {
            int i2 = idx / SIT, k = idx % SIT;
            D[((k >> 2) * S2 + i2) * 4 + (k & 3)] = S[idx];
        }
    } else {
        // MFMA B-fragment pack: UB[idx], idx = nb*8192 + ks*512 + lane*8 + j
        // value = U[nb*16 + (lane&15)][ks*32 + (lane>>4)*8 + j] - diag
        const float* S = (y == 5) ? Uz : (y == 6) ? Ur : Uh;
        unsigned short* D = (y == 5) ? UBz : (y == 6) ? UBr : UBh;
        if (idx < S2 * S2) {
            int j = idx & 7;
            int lane = (idx >> 3) & 63;
            int ks = (idx >> 9) & 15;
            int nb = idx >> 13;
            int row = nb * 16 + (lane & 15);
            int col = ks * 32 + (lane >> 4) * 8 + j;
            float v = S[row * S2 + col] - ((row == col) ? DIAG : 0.f);
            D[idx] = f2bf_(v);
        }
    }
}

__global__ void k_copy(const float4* __restrict__ src, float4* dst, int n4) {
    int i = blockIdx.x * blockDim.x + threadIdx.x;
    if (i < n4) dst[i] = src[i];
}

// XP = W@x + bias for all steps
__global__ __launch_bounds__(512) void k_xp(
    const float* __restrict__ x,
    const float* __restrict__ WzT, const float* __restrict__ WrT, const float* __restrict__ WhT,
    const float* __restrict__ bz, const float* __restrict__ br, const float* __restrict__ bh,
    float* __restrict__ XPz, float* __restrict__ XPr, float* __restrict__ XPh)
{
    __shared__ float xs[16][SIT];
    const int i = threadIdx.x;
    const int tile = blockIdx.x;
    const float4* Wz4 = (const float4*)WzT;
    const float4* Wr4 = (const float4*)WrT;
    const float4* Wh4 = (const float4*)WhT;
    const float bzi = bz[i], bri = br[i], bhi = bh[i];

    for (int idx = i; idx < 16 * SIT; idx += 512) {
        int j = idx >> 6, k = idx & (SIT - 1);
        xs[j][k] = x[(tile * 16 + j) * SIT + k];
    }
    __syncthreads();
    float za[16], ra[16], ha[16];
#pragma unroll
    for (int j = 0; j < 16; ++j) { za[j] = 0.f; ra[j] = 0.f; ha[j] = 0.f; }
    for (int kb = 0; kb < WKB; ++kb) {
        float4 wz = Wz4[kb * S2 + i];
        float4 wr = Wr4[kb * S2 + i];
        float4 wh = Wh4[kb * S2 + i];
#pragma unroll
        for (int j = 0; j < 16; ++j) {
            float4 x4 = *(const float4*)(&xs[j][kb * 4]);
            za[j] += dot4_(wz, x4);
            ra[j] += dot4_(wr, x4);
            ha[j] += dot4_(wh, x4);
        }
    }
#pragma unroll
    for (int j = 0; j < 16; ++j) {
        int t = tile * 16 + j;
        XPz[t * S2 + i] = za[j] + bzi;
        XPr[t * S2 + i] = ra[j] - bri;
        XPh[t * S2 + i] = ha[j] + bhi;
    }
}

// ---------------- main cooperative kernel ----------------

// Phase A tile via MFMA. pool layout (floats):
// [0..8191] Hs f32 [16][512]; [8192..12287] Hbf (bf16, A-frag layout);
// [12288..16383] RHbf (bf16, A-frag layout); [16384..17407] xs (fallback).
__device__ __forceinline__ void tile_mfma(
    int sbase, int B, int i,
    const int* __restrict__ bArr, const int* __restrict__ pArr,
    const unsigned short* __restrict__ UBz, const unsigned short* __restrict__ UBr,
    const unsigned short* __restrict__ UBh,
    const float* __restrict__ XPz, const float* __restrict__ XPr, const float* __restrict__ XPh,
    float* __restrict__ out, const int* __restrict__ order,
    float* pool, int* tj, int* rbs, int* rps)
{
    unsigned short* Hbf  = (unsigned short*)(pool + 8192);
    unsigned short* RHbf = (unsigned short*)(pool + 12288);
    unsigned* H32 = (unsigned*)Hbf;
    const short8* BzF = (const short8*)UBz;
    const short8* BrF = (const short8*)UBr;
    const short8* BhF = (const short8*)UBh;
    const short8* AF  = (const short8*)Hbf;
    const short8* RF  = (const short8*)RHbf;
    const int lane = i & 63;
    const int w = i >> 6;

    __syncthreads();                       // guard LDS reuse
    if (i < 16) {
        int t = (i < B) ? order[sbase + i] : -1;
        tj[i] = t;
        rbs[i] = (t >= 0) ? bArr[t] : 0;
        rps[i] = (t >= 0) ? pArr[t] : 0;
    }
    __syncthreads();

    // gather h -> Hs (f32) + Hbf (bf16 A-fragment layout, u32-packed writes)
    for (int idx2 = i; idx2 < 16 * 256; idx2 += 512) {
        int j = idx2 >> 8, kp = (idx2 & 255) << 1;    // kp even
        float v0 = 0.0f, v1 = 0.0f;
        if (tj[j] >= 0) {
            int row = (kp < SS) ? rbs[j] : rps[j];
            const float* rowp = out + row * SS + (kp & (SS - 1));
            v0 = rowp[0];
            v1 = rowp[1];
        }
        pool[j * S2 + kp] = v0;
        pool[j * S2 + kp + 1] = v1;
        int ks = kp >> 5, kk = kp & 31;
        H32[((((ks << 6) + j + ((kk >> 3) << 4)) << 3) + (kk & 7)) >> 1] = pk2_(v0, v1);
    }
    __syncthreads();

    // ---- z/r MFMA pass: wave w owns col-blocks w*4 .. w*4+3 ----
    f32x4 accz[4], accr[4];
#pragma unroll
    for (int nb2 = 0; nb2 < 4; ++nb2) {
        accz[nb2] = (f32x4){0.f, 0.f, 0.f, 0.f};
        accr[nb2] = (f32x4){0.f, 0.f, 0.f, 0.f};
    }
#pragma unroll 1
    for (int ks = 0; ks < 16; ++ks) {
        short8 a = AF[(ks << 6) + lane];
#pragma unroll
        for (int nb2 = 0; nb2 < 4; ++nb2) {
            int nb = w * 4 + nb2;
            short8 bz = BzF[((nb << 4) + ks) * 64 + lane];
            short8 br = BrF[((nb << 4) + ks) * 64 + lane];
            accz[nb2] = __builtin_amdgcn_mfma_f32_16x16x32_bf16(a, bz, accz[nb2], 0, 0, 0);
            accr[nb2] = __builtin_amdgcn_mfma_f32_16x16x32_bf16(a, br, accr[nb2], 0, 0, 0);
        }
    }
    // epilogue 1: activations, write RHbf
    f32x4 zv[4];
#pragma unroll
    for (int nb2 = 0; nb2 < 4; ++nb2) {
        int c = (w * 4 + nb2) * 16 + (lane & 15);
#pragma unroll
        for (int q = 0; q < 4; ++q) {
            int m = ((lane >> 4) << 2) + q;
            int t = tj[m];
            float h = pool[m * S2 + c];
            float xpz = (t >= 0) ? XPz[t * S2 + c] : 0.f;
            float xpr = (t >= 0) ? XPr[t * S2 + c] : 0.f;
            float zpre = accz[nb2][q] + xpz + DIAG * h;
            float rpre = accr[nb2][q] + xpr + DIAG * h;
            zv[nb2][q] = sigmoidf_(zpre);
            float rh = (t >= 0) ? sigmoidf_(rpre) * h : 0.f;
            int ks = c >> 5, kk = c & 31;
            RHbf[((ks << 6) + m + ((kk >> 3) << 4)) * 8 + (kk & 7)] = f2bf_(rh);
        }
    }
    __syncthreads();                        // RHbf ready

    // ---- m MFMA pass ----
    f32x4 accm[4];
#pragma unroll
    for (int nb2 = 0; nb2 < 4; ++nb2) accm[nb2] = (f32x4){0.f, 0.f, 0.f, 0.f};
#pragma unroll 1
    for (int ks = 0; ks < 16; ++ks) {
        short8 a = RF[(ks << 6) + lane];
#pragma unroll
        for (int nb2 = 0; nb2 < 4; ++nb2) {
            int nb = w * 4 + nb2;
            short8 bh = BhF[((nb << 4) + ks) * 64 + lane];
            accm[nb2] = __builtin_amdgcn_mfma_f32_16x16x32_bf16(a, bh, accm[nb2], 0, 0, 0);
        }
    }
    // epilogue 2: hn, scatter
#pragma unroll
    for (int nb2 = 0; nb2 < 4; ++nb2) {
        int c = (w * 4 + nb2) * 16 + (lane & 15);
#pragma unroll
        for (int q = 0; q < 4; ++q) {
            int m = ((lane >> 4) << 2) + q;
            int t = tj[m];
            if (t >= 0) {
                float h = pool[m * S2 + c];
                int ks = c >> 5, kk = c & 31;
                float rh = __uint_as_float(
                    ((unsigned)RHbf[((ks << 6) + m + ((kk >> 3) << 4)) * 8 + (kk & 7)]) << 16);
                float mm = tanhf(accm[nb2][q] + XPh[t * S2 + c] + DIAG * rh);
                float z = zv[nb2][q];
                float hn = z * h + (1.f - z) * mm;
                int rb = rbs[m], rp = rps[m];
                int row = (c < SS) ? rb : rp;
                float* addr = out + row * SS + (c & (SS - 1));
                if (rb == rp) atomicAdd(addr, hn - h);
                else *addr = hn;
            }
        }
    }
}

// VALU fallback tile body (only used when !useXP) — R11-proven.
template<int BQ>
__device__ __forceinline__ void process_level_valu(
    int s0, int s1, int i,
    const float* __restrict__ x,
    const int* __restrict__ bArr, const int* __restrict__ pArr,
    const float4* __restrict__ Wz4, const float4* __restrict__ Wr4, const float4* __restrict__ Wh4,
    const uint4* __restrict__ Uzr, const uint2* __restrict__ Uhp,
    float bzi, float bri, float bhi,
    float* __restrict__ out, const int* __restrict__ order,
    float* pool, int* tj, int* rbs, int* rps)
{
    float* Hsf = pool;
    float* RHf = pool + 8192;
    float* xsf = pool + 16384;
    const int nT = (s1 - s0 + BQ - 1) / BQ;
    for (int tile = blockIdx.x; tile < nT; tile += gridDim.x) {
        const int sbase = s0 + tile * BQ;
        const int B = (sbase + BQ <= s1) ? BQ : (s1 - sbase);
        __syncthreads();
        if (i < BQ) {
            int t = (i < B) ? order[sbase + i] : -1;
            tj[i] = t;
            rbs[i] = (t >= 0) ? bArr[t] : 0;
            rps[i] = (t >= 0) ? pArr[t] : 0;
        }
        __syncthreads();
        for (int idx = i; idx < BQ * S2; idx += 512) {
            int j = idx >> 9, k = idx & (S2 - 1);
            float v = 0.0f;
            if (tj[j] >= 0) {
                int row = (k < SS) ? rbs[j] : rps[j];
                v = out[row * SS + (k & (SS - 1))];
            }
            Hsf[j * S2 + k] = v;
        }
        for (int idx = i; idx < BQ * SIT; idx += 512) {
            int j = idx >> 6, k = idx & (SIT - 1);
            int t = tj[j];
            xsf[j * SIT + k] = (t >= 0) ? x[t * SIT + k] : 0.0f;
        }
        float zacc[BQ], racc[BQ];
#pragma unroll
        for (int j = 0; j < BQ; ++j) { zacc[j] = 0.0f; racc[j] = 0.0f; }
        __syncthreads();
        for (int kb = 0; kb < WKB; ++kb) {
            float4 a4 = Wz4[kb * S2 + i];
            float4 b4 = Wr4[kb * S2 + i];
#pragma unroll
            for (int j = 0; j < BQ; ++j) {
                float4 x4 = *(const float4*)(&xsf[j * SIT + kb * 4]);
                zacc[j] += dot4_(a4, x4);
                racc[j] += dot4_(b4, x4);
            }
        }
        for (int kb = 0; kb < NKB; ++kb) {
            uint4 u = Uzr[kb * S2 + i];
#pragma unroll
            for (int j = 0; j < BQ; ++j) {
                float4 h4 = *(const float4*)(&Hsf[j * S2 + kb * 4]);
                zacc[j] += bflo_(u.x) * h4.x + bfhi_(u.x) * h4.y + bflo_(u.y) * h4.z + bfhi_(u.y) * h4.w;
                racc[j] += bflo_(u.z) * h4.x + bfhi_(u.z) * h4.y + bflo_(u.w) * h4.z + bfhi_(u.w) * h4.w;
            }
        }
        float zv[BQ];
#pragma unroll
        for (int j = 0; j < BQ; ++j) {
            float hOwn = Hsf[j * S2 + i];
            zv[j] = sigmoidf_(zacc[j] + DIAG * hOwn + bzi);
            RHf[j * S2 + i] = sigmoidf_(racc[j] + DIAG * hOwn - bri) * hOwn;
        }
        __syncthreads();
        float macc[BQ];
#pragma unroll
        for (int j = 0; j < BQ; ++j) macc[j] = 0.0f;
        for (int kb = 0; kb < WKB; ++kb) {
            float4 a4 = Wh4[kb * S2 + i];
#pragma unroll
            for (int j = 0; j < BQ; ++j) {
                float4 x4 = *(const float4*)(&xsf[j * SIT + kb * 4]);
                macc[j] += dot4_(a4, x4);
            }
        }
        for (int kb = 0; kb < NKB; ++kb) {
            uint2 u = Uhp[kb * S2 + i];
#pragma unroll
            for (int j = 0; j < BQ; ++j) {
                float4 h4 = *(const float4*)(&RHf[j * S2 + kb * 4]);
                macc[j] += bflo_(u.x) * h4.x + bfhi_(u.x) * h4.y + bflo_(u.y) * h4.z + bfhi_(u.y) * h4.w;
            }
        }
        for (int j = 0; j < B; ++j) {
            float mm = tanhf(macc[j] + DIAG * RHf[j * S2 + i] + bhi);
            float h = Hsf[j * S2 + i];
            float hn = zv[j] * h + (1.0f - zv[j]) * mm;
            int rb = rbs[j], rp = rps[j];
            int row = (i < SS) ? rb : rp;
            float* addr = out + row * SS + (i & (SS - 1));
            if (rb == rp) atomicAdd(addr, hn - h);
            else *addr = hn;
        }
    }
}

__global__ __launch_bounds__(512, 4) void k_main(
    const float* __restrict__ x, const int* __restrict__ bArr, const int* __restrict__ pArr,
    const float* __restrict__ WzT, const float* __restrict__ WrT, const float* __restrict__ WhT,
    const uint4* __restrict__ Uzr, const uint2* __restrict__ Uhp,
    const unsigned short* __restrict__ UBz, const unsigned short* __restrict__ UBr,
    const unsigned short* __restrict__ UBh,
    const float* __restrict__ bz, const float* __restrict__ br, const float* __restrict__ bh,
    float* __restrict__ out,
    const int* __restrict__ order, const int* __restrict__ levelStart,
    const int* __restrict__ numLevels,
    const float* __restrict__ XPz, const float* __restrict__ XPr, const float* __restrict__ XPh,
    const int* __restrict__ pred, int* __restrict__ flagArr,
    int* __restrict__ rhCnt, float* __restrict__ RHstage,
    int useXP, int useSlice)
{
    cg::grid_group grid = cg::this_grid();
    __shared__ float pool[17408];
    __shared__ int tj[BQMAX], rbs[BQMAX], rps[BQMAX];

    const int i = threadIdx.x;
    const float bzi = bz[i], bri = br[i], bhi = bh[i];
    const float4* Wz4 = (const float4*)WzT;
    const float4* Wr4 = (const float4*)WrT;
    const float4* Wh4 = (const float4*)WhT;

    const int cutoff = numLevels[1];

    // ---- phase A ----
    for (int lvl = 1; lvl <= cutoff; ++lvl) {
        const int s0 = levelStart[lvl - 1], s1 = levelStart[lvl];
        if (useXP) {
            const int nT = (s1 - s0 + 15) / 16;
            for (int tile = blockIdx.x; tile < nT; tile += gridDim.x) {
                const int sbase = s0 + tile * 16;
                const int B = (sbase + 16 <= s1) ? 16 : (s1 - sbase);
                tile_mfma(sbase, B, i, bArr, pArr, UBz, UBr, UBh,
                          XPz, XPr, XPh, out, order, pool, tj, rbs, rps);
            }
        } else {
            process_level_valu<8>(s0, s1, i, x, bArr, pArr, Wz4, Wr4, Wh4,
                                  Uzr, Uhp, bzi, bri, bhi, out, order,
                                  pool, tj, rbs, rps);
        }
        grid.sync();
    }

    const int sB = levelStart[cutoff];
    const int nB = T_STEPS - sB;

    for (int s = blockIdx.x * 512 + i; s < T_STEPS; s += gridDim.x * 512)
        flagArr[order[s]] = (s < sB) ? NSLICE : 0;
    for (int c = blockIdx.x * 512 + i; c < MAXB; c += gridDim.x * 512)
        rhCnt[c] = 0;
    grid.sync();

    float* Hs0 = pool;
    float* PB1 = pool + 8192;
    float* PB2 = pool + 8704;
    float* PB3 = pool + 9216;
    float* RHs0 = pool + 9728;
    float* xs0 = pool + 16384;

    if (useSlice && nB <= MAXB) {
        // ---- phase B (sliced): 4 blocks per step ----
        const int jr = i & 127;
        const int ks = i >> 7;
        for (int g = blockIdx.x; g < NSLICE * nB; g += gridDim.x) {
            const int s = sB + (g >> 2);
            const int q = g & 3;
            const int t = order[s];
            const int slot = s - sB;
            if (i == 0) {
                int p0 = pred[2 * t], p1 = pred[2 * t + 1];
                while (p0 >= 0 && __hip_atomic_load(&flagArr[p0], __ATOMIC_ACQUIRE,
                                                    __HIP_MEMORY_SCOPE_AGENT) < NSLICE)
                    __builtin_amdgcn_s_sleep(2);
                while (p1 >= 0 && __hip_atomic_load(&flagArr[p1], __ATOMIC_ACQUIRE,
                                                    __HIP_MEMORY_SCOPE_AGENT) < NSLICE)
                    __builtin_amdgcn_s_sleep(2);
            }
            __syncthreads();

            const int rb = bArr[t], rp = pArr[t];
            {
                const int row = (i < SS) ? rb : rp;
                Hs0[i] = loadLLC_(out + row * SS + (i & (SS - 1)));
            }
            __syncthreads();

            const int myrow = q * 128 + jr;
            const int kb0 = ks * 32;
            float zp = 0.f, rpv = 0.f;
            for (int kb = kb0; kb < kb0 + 32; ++kb) {
                uint4 u = Uzr[kb * S2 + myrow];
                float4 h4 = *(const float4*)(&Hs0[kb * 4]);
                zp  += bflo_(u.x) * h4.x + bfhi_(u.x) * h4.y + bflo_(u.y) * h4.z + bfhi_(u.y) * h4.w;
                rpv += bflo_(u.z) * h4.x + bfhi_(u.z) * h4.y + bflo_(u.w) * h4.z + bfhi_(u.w) * h4.w;
            }
            PB1[ks * 128 + jr] = zp;
            PB2[ks * 128 + jr] = rpv;
            __syncthreads();
            if (i < 128) {
                float hOwn = Hs0[q * 128 + i];
                float zsum = XPz[t * S2 + q * 128 + i] + DIAG * hOwn
                           + PB1[i] + PB1[128 + i] + PB1[256 + i] + PB1[384 + i];
                float rsum = XPr[t * S2 + q * 128 + i] + DIAG * hOwn
                           + PB2[i] + PB2[128 + i] + PB2[256 + i] + PB2[384 + i];
                float zvv = sigmoidf_(zsum);
                float rh = sigmoidf_(rsum) * hOwn;
                storeLLC_(RHstage + (size_t)slot * S2 + q * 128 + i, rh);
                PB3[i] = zvv;
            }
            __syncthreads();
            if (i == 0) {
                __hip_atomic_fetch_add(&rhCnt[slot], 1, __ATOMIC_RELEASE,
                                       __HIP_MEMORY_SCOPE_AGENT);
                while (__hip_atomic_load(&rhCnt[slot], __ATOMIC_ACQUIRE,
                                         __HIP_MEMORY_SCOPE_AGENT) < NSLICE)
                    __builtin_amdgcn_s_sleep(1);
            }
            __syncthreads();
            RHs0[i] = loadLLC_(RHstage + (size_t)slot * S2 + i);
            __syncthreads();

            float mp = 0.f;
            for (int kb = kb0; kb < kb0 + 32; ++kb) {
                uint2 u = Uhp[kb * S2 + myrow];
                float4 h4 = *(const float4*)(&RHs0[kb * 4]);
                mp += bflo_(u.x) * h4.x + bfhi_(u.x) * h4.y + bflo_(u.y) * h4.z + bfhi_(u.y) * h4.w;
            }
            PB1[ks * 128 + jr] = mp;
            __syncthreads();
            if (i < 128) {
                float msum = XPh[t * S2 + q * 128 + i] + DIAG * RHs0[q * 128 + i]
                           + PB1[i] + PB1[128 + i] + PB1[256 + i] + PB1[384 + i];
                float mm = tanhf(msum);
                float zz = PB3[i];
                float h0 = Hs0[q * 128 + i];
                float hn = zz * h0 + (1.f - zz) * mm;
                int grow = q * 128 + i;
                int orow = (grow < SS) ? rb : rp;
                float* addr = out + orow * SS + (grow & (SS - 1));
                if (rb == rp) atomicAdd(addr, hn - h0);
                else storeLLC_(addr, hn);
            }
            __syncthreads();
            if (i == 0)
                __hip_atomic_fetch_add(&flagArr[t], 1, __ATOMIC_RELEASE,
                                       __HIP_MEMORY_SCOPE_AGENT);
        }
    } else {
        // ---- phase B fallback: one block per step ----
        for (int s = sB + blockIdx.x; s < T_STEPS; s += gridDim.x) {
            const int t = order[s];
            if (i == 0) {
                int p0 = pred[2 * t], p1 = pred[2 * t + 1];
                while (p0 >= 0 && __hip_atomic_load(&flagArr[p0], __ATOMIC_ACQUIRE,
                                                    __HIP_MEMORY_SCOPE_AGENT) < NSLICE)
                    __builtin_amdgcn_s_sleep(2);
                while (p1 >= 0 && __hip_atomic_load(&flagArr[p1], __ATOMIC_ACQUIRE,
                                                    __HIP_MEMORY_SCOPE_AGENT) < NSLICE)
                    __builtin_amdgcn_s_sleep(2);
            }
            __syncthreads();

            const int rb = bArr[t], rp = pArr[t];
            const int row = (i < SS) ? rb : rp;
            float* addr = out + row * SS + (i & (SS - 1));
            const float h = loadLLC_(addr);
            Hs0[i] = h;
            float zacc, racc;
            if (useXP) {
                zacc = XPz[t * S2 + i];
                racc = XPr[t * S2 + i];
            } else {
                zacc = 0.0f; racc = 0.0f;
                if (i < SIT) xs0[i] = x[t * SIT + i];
            }
            __syncthreads();

            if (!useXP) {
                for (int kb = 0; kb < WKB; ++kb) {
                    float4 a4 = Wz4[kb * S2 + i];
                    float4 b4 = Wr4[kb * S2 + i];
                    float4 x4 = *(const float4*)(&xs0[kb * 4]);
                    zacc += dot4_(a4, x4);
                    racc += dot4_(b4, x4);
                }
            }
            for (int kb = 0; kb < NKB; ++kb) {
                uint4 u = Uzr[kb * S2 + i];
                float4 h4 = *(const float4*)(&Hs0[kb * 4]);
                zacc += bflo_(u.x) * h4.x + bfhi_(u.x) * h4.y + bflo_(u.y) * h4.z + bfhi_(u.y) * h4.w;
                racc += bflo_(u.z) * h4.x + bfhi_(u.z) * h4.y + bflo_(u.w) * h4.z + bfhi_(u.w) * h4.w;
            }
            const float zvv = sigmoidf_(zacc + DIAG * h + (useXP ? 0.f : bzi));
            const float rv = sigmoidf_(racc + DIAG * h - (useXP ? 0.f : bri));
            RHs0[i] = rv * h;
            __syncthreads();

            float macc;
            if (useXP) {
                macc = XPh[t * S2 + i];
            } else {
                macc = 0.0f;
                for (int kb = 0; kb < WKB; ++kb) {
                    float4 a4 = Wh4[kb * S2 + i];
                    float4 x4 = *(const float4*)(&xs0[kb * 4]);
                    macc += dot4_(a4, x4);
                }
            }
            for (int kb = 0; kb < NKB; ++kb) {
                uint2 u = Uhp[kb * S2 + i];
                float4 h4 = *(const float4*)(&RHs0[kb * 4]);
                macc += bflo_(u.x) * h4.x + bfhi_(u.x) * h4.y + bflo_(u.y) * h4.z + bfhi_(u.y) * h4.w;
            }
            const float mm = tanhf(macc + DIAG * RHs0[i] + (useXP ? 0.f : bhi));
            const float hn = zvv * h + (1.0f - zvv) * mm;
            if (rb == rp) atomicAdd(addr, hn - h);
            else storeLLC_(addr, hn);
            __syncthreads();
            if (i == 0)
                __hip_atomic_fetch_add(&flagArr[t], NSLICE, __ATOMIC_RELEASE,
                                       __HIP_MEMORY_SCOPE_AGENT);
        }
    }
}

// ---------------- host launcher ----------------

extern "C" void kernel_launch(void* const* d_in, const int* in_sizes, int n_in,
                              void* d_out, int out_size, void* d_ws, size_t ws_size,
                              hipStream_t stream) {
    const float* x  = (const float*)d_in[0];
    const int*   b  = (const int*)d_in[1];
    const int*   p  = (const int*)d_in[2];
    const float* Wz = (const float*)d_in[3];
    const float* Wr = (const float*)d_in[4];
    const float* Wh = (const float*)d_in[5];
    const float* Uz = (const float*)d_in[6];
    const float* Ur = (const float*)d_in[7];
    const float* Uh = (const float*)d_in[8];
    const float* bz = (const float*)d_in[9];
    const float* br = (const float*)d_in[10];
    const float* bh = (const float*)d_in[11];
    const float* table0 = (const float*)d_in[12];
    float* out = (float*)d_out;

    float* base = (float*)d_ws;
    uint4* UzrP = (uint4*)base;
    uint2* UhP  = (uint2*)(base + 262144);
    unsigned short* UBz = (unsigned short*)(base + 262144 + 131072);
    unsigned short* UBr = (unsigned short*)(base + 262144 + 2 * 131072);
    unsigned short* UBh = (unsigned short*)(base + 262144 + 3 * 131072);
    float* WzT  = base + 262144 + 4 * 131072;
    float* WrT  = WzT + S2 * SIT;
    float* WhT  = WrT + S2 * SIT;
    int* cnt = (int*)(WhT + S2 * SIT);
    int* cur = cnt + NPL;
    int* bas = cur + NPL;
    int* list = bas + NPL;
    int* pred = list + NEV;
    int* order = pred + NEV;
    int* levelStart = order + T_STEPS;
    int* numLevels = levelStart + 260;
    int* flagArr = numLevels + 4;
    int* rhCnt = flagArr + T_STEPS;

    size_t baseFloats = (size_t)262144 + 4 * 131072 + 3 * S2 * SIT
                      + 3 * NPL + 2 * NEV + T_STEPS + 264 + T_STEPS + MAXB;
    baseFloats = (baseFloats + 255) & ~(size_t)255;
    float* RHstage = base + baseFloats;
    size_t rhFloats = (size_t)MAXB * S2;
    size_t xpFloats = 3ull * T_STEPS * S2;

    int useSlice = 0, useXP = 0;
    float *XPz;
    if (ws_size >= (baseFloats + rhFloats + xpFloats) * 4ull) {
        useSlice = 1; useXP = 1; XPz = RHstage + rhFloats;
    } else if (ws_size >= (baseFloats + xpFloats) * 4ull) {
        useXP = 1; XPz = RHstage;
    } else {
        XPz = RHstage;
    }
    float* XPr = XPz + (size_t)T_STEPS * S2;
    float* XPh = XPr + (size_t)T_STEPS * S2;

    hipMemsetAsync(cnt, 0, NPL * sizeof(int), stream);
    hipLaunchKernelGGL(k_trans, dim3(1024, 8), dim3(256), 0, stream,
                       Uz, Ur, Uh, Wz, Wr, Wh, UzrP, UhP, UBz, UBr, UBh, WzT, WrT, WhT);
    hipLaunchKernelGGL(k_count, dim3((NEV + 255) / 256), dim3(256), 0, stream, b, p, cnt);
    hipLaunchKernelGGL(k_scan, dim3(1), dim3(1024), 0, stream, cnt, bas, cur);
    hipLaunchKernelGGL(k_place, dim3((NEV + 255) / 256), dim3(256), 0, stream, b, p, cur, list);
    hipLaunchKernelGGL(k_pred, dim3((NPL + 255) / 256), dim3(256), 0, stream, bas, cnt, list, pred);
    hipLaunchKernelGGL(k_levels, dim3(1), dim3(1024), 0, stream,
                       pred, order, levelStart, numLevels);

    int n4 = NPL * SS / 4;
    hipLaunchKernelGGL(k_copy, dim3((n4 + 255) / 256), dim3(256), 0, stream,
                       (const float4*)table0, (float4*)out, n4);
    if (useXP) {
        hipLaunchKernelGGL(k_xp, dim3(T_STEPS / 16), dim3(512), 0, stream,
                           x, WzT, WrT, WhT, bz, br, bh, XPz, XPr, XPh);
    }

    int occ = 0;
    if (hipOccupancyMaxActiveBlocksPerMultiprocessor(&occ, k_main, 512, 0) != hipSuccess)
        occ = 1;
    if (occ < 1) occ = 1;
    if (occ > 2) occ = 2;
    int gridSz = occ * 256;

    void* args[] = {
        (void*)&x, (void*)&b, (void*)&p,
        (void*)&WzT, (void*)&WrT, (void*)&WhT,
        (void*)&UzrP, (void*)&UhP,
        (void*)&UBz, (void*)&UBr, (void*)&UBh,
        (void*)&bz, (void*)&br, (void*)&bh,
        (void*)&out,
        (void*)&order, (void*)&levelStart, (void*)&numLevels,
        (void*)&XPz, (void*)&XPr, (void*)&XPh,
        (void*)&pred, (void*)&flagArr, (void*)&rhCnt, (void*)&RHstage,
        (void*)&useXP, (void*)&useSlice
    };
    hipError_t e = hipLaunchCooperativeKernel((void*)k_main, dim3(gridSz), dim3(512), args, 0, stream);
    if (e != hipSuccess && gridSz != 256) {
        hipLaunchCooperativeKernel((void*)k_main, dim3(256), dim3(512), args, 0, stream);
    }
}